// Round 9
// baseline (358.031 us; speedup 1.0000x reference)
//
#include <hip/hip_runtime.h>
#include <hip/hip_bf16.h>

typedef unsigned short u16;
typedef unsigned int   u32;
typedef __attribute__((ext_vector_type(8))) __bf16 bf16x8;
typedef __attribute__((ext_vector_type(4))) float  f32x4;
typedef __attribute__((ext_vector_type(8))) u16    u16x8;
typedef __attribute__((ext_vector_type(4))) u16    u16x4;
typedef __attribute__((ext_vector_type(2))) u32    u32x2;
typedef __attribute__((ext_vector_type(4))) u32    u32x4;

#define S_LEN 2048
#define DMODEL 4096
#define NH 64
#define NKV 4
#define HD 64

__device__ __forceinline__ u16 f2bf(float f) {
  u32 u = __builtin_bit_cast(u32, f);
  u32 r = (u + 0x7FFFu + ((u >> 16) & 1u)) >> 16;
  return (u16)r;
}
__device__ __forceinline__ u16 bfc(float f) {
  return __builtin_bit_cast(u16, (__bf16)f);
}
__device__ __forceinline__ u32 pk2(float lo, float hi) {
  return (u32)bfc(lo) | ((u32)bfc(hi) << 16);
}
__device__ __forceinline__ float bf2f(u16 u) {
  return __builtin_bit_cast(float, (u32)u << 16);
}
__device__ __forceinline__ float ex2(float x) { return __builtin_amdgcn_exp2f(x); }

__device__ __forceinline__ void gll16(const void* g, void* l) {
  __builtin_amdgcn_global_load_lds(
      (__attribute__((address_space(1))) void*)g,
      (__attribute__((address_space(3))) void*)l, 16, 0, 0);
}

// ---------------- elementwise converts ----------------
__global__ __launch_bounds__(256) void cvt_f32_bf16_v4(const float* __restrict__ in,
                                                       u16* __restrict__ out) {
  const int i = blockIdx.x * 256 + threadIdx.x;
  float4 f = ((const float4*)in)[i];
  u16x4 u = { f2bf(f.x), f2bf(f.y), f2bf(f.z), f2bf(f.w) };
  *(u16x4*)&out[(size_t)i * 4] = u;
}

// transpose-convert: in fp32 R x C (row stride istride) -> out bf16 C x R.
__global__ __launch_bounds__(256) void tconvs(const float* __restrict__ in, int istride,
                                              u16* __restrict__ out, int R, int C) {
  __shared__ __align__(16) float tile[32][36];
  const int nc = C >> 5;
  const int cb = blockIdx.x % nc, rb = blockIdx.x / nc;
  const int r = threadIdx.x >> 3, c4 = (threadIdx.x & 7) << 2;
  float4 v = *(const float4*)&in[(size_t)(rb * 32 + r) * istride + cb * 32 + c4];
  *(float4*)&tile[r][c4] = v;
  __syncthreads();
  u32x2 pr;
  pr[0] = pk2(tile[c4 + 0][r], tile[c4 + 1][r]);
  pr[1] = pk2(tile[c4 + 2][r], tile[c4 + 3][r]);
  *(u32x2*)&out[(size_t)(cb * 32 + r) * R + rb * 32 + c4] = pr;
}

// bf16 transpose: in R x C (row stride istride) -> out C x R.
__global__ __launch_bounds__(256) void tconvb(const u16* __restrict__ in, int istride,
                                              u16* __restrict__ out, int R, int C) {
  __shared__ __align__(16) u16 tile[32][40];
  const int nc = C >> 5;
  const int cb = blockIdx.x % nc, rb = blockIdx.x / nc;
  const int r = threadIdx.x >> 3, c4 = (threadIdx.x & 7) << 2;
  u16x4 v = *(const u16x4*)&in[(size_t)(rb * 32 + r) * istride + cb * 32 + c4];
  *(u16x4*)&tile[r][c4] = v;
  __syncthreads();
  u16x4 o = { tile[c4 + 0][r], tile[c4 + 1][r], tile[c4 + 2][r], tile[c4 + 3][r] };
  *(u16x4*)&out[(size_t)(cb * 32 + r) * R + rb * 32 + c4] = o;
}

// ---------------- RMSNorm + RoPE, bf16 input (one wave = one (s,head) row) ------
__global__ __launch_bounds__(256) void norm_rope_q(const u16* __restrict__ in,
                                                   int in_stride, int nheads,
                                                   const float* __restrict__ nw,
                                                   const float* __restrict__ cosT,
                                                   const float* __restrict__ sinT,
                                                   u16* __restrict__ outp, int out_stride,
                                                   float oscale) {
  const int wid = blockIdx.x * 4 + (threadIdx.x >> 6);
  const int l = threadIdx.x & 63;
  const int s = wid / nheads, h = wid - s * nheads;
  const size_t idx = (size_t)s * in_stride + h * 64 + l;
  const float v = bf2f(in[idx]);
  float sq = v * v;
#pragma unroll
  for (int off = 32; off; off >>= 1) sq += __shfl_xor(sq, off, 64);
  const float rr = rsqrtf(sq * (1.f / 64.f) + 1e-5f);
  const float vn = v * rr * nw[l];
  const float p = __shfl_xor(vn, 1, 64);
  const int i2 = l >> 1;
  const float c = cosT[(size_t)s * 32 + i2];
  const float sn = sinT[(size_t)s * 32 + i2];
  const float o = ((l & 1) ? fmaf(p, sn, vn * c) : fmaf(-p, sn, vn * c)) * oscale;
  outp[(size_t)s * out_stride + h * 64 + l] = f2bf(o);
}

// ---------------- big GEMM: 128x128 tile, FULL-K, 8 waves (4Mx2N, 32x64/wave) ----
// LDS 64KB = 4 pages x 16KB; page = 32-k slice { A 8KB | B 8KB }. 2 blocks/CU.
// Depth-3 prefetch, 2 loads/stage, steady vmcnt(4). 128B LDS rows pack two rows'
// 64B k-slices; 16B slots XOR-swizzled.
template <int BF16OUT>
__global__ __launch_bounds__(512, 2) void gemm_mn(const u16* __restrict__ A,
                                                  const u16* __restrict__ Bt,
                                                  void* __restrict__ Cout,
                                                  int M, int N, int K) {
  extern __shared__ __align__(16) char lds[];
  int bid = blockIdx.x;
  const int cpx = gridDim.x >> 3;
  bid = (bid & 7) * cpx + (bid >> 3);
  const int nbn = N >> 7;
  const int bm = bid / nbn, bn = bid % nbn;
  const int m0 = bm << 7, n0 = bn << 7;
  const int t = threadIdx.x, w = t >> 6, l = t & 63;
  const int wr = w >> 1, wc = w & 1;            // waves 4(M) x 2(N); per-wave 32x64
  const int lr = l & 15, lg = l >> 4;

  const int sR = t >> 3, slot = t & 7;
  const int su = slot ^ (sR & 7);
  const int d1 = sR * 128 + slot * 16;
  const u16* Ag = A + (size_t)(m0 + 2 * sR + (su >> 2)) * K + (su & 3) * 8;
  const u16* Bg = Bt + (size_t)(n0 + 2 * sR + (su >> 2)) * K + (su & 3) * 8;

  f32x4 acc[2][4] = {};
  const int NPH = K >> 5;

  auto stage = [&](int ph) {
    const int kofs = ph * 32;
    char* pb = lds + (ph & 3) * 16384;
    gll16(Ag + kofs, pb + d1);                 // A m 0..127 (2 per 128B row)
    gll16(Bg + kofs, pb + 8192 + d1);          // B n 0..127
  };
  stage(0);
  stage(1);
  stage(2);

  const int sfrag = ((lr & 1) << 2) | lg;
  const int swz = (sfrag ^ ((lr >> 1) & 7)) << 4;
  const int aoff = (wr * 16 + (lr >> 1)) * 128 + swz;          // wave covers 32 m = 16 rows
  const int boff = 8192 + (wc * 32 + (lr >> 1)) * 128 + swz;   // wave covers 64 n = 32 rows

  auto compute = [&](int ph) {
    const char* base = lds + (ph & 3) * 16384;
    bf16x8 a[2], b[4];
#pragma unroll
    for (int mf = 0; mf < 2; ++mf) a[mf] = *(const bf16x8*)(base + aoff + mf * 1024);
#pragma unroll
    for (int nf = 0; nf < 4; ++nf) b[nf] = *(const bf16x8*)(base + boff + nf * 1024);
    __builtin_amdgcn_s_setprio(1);
#pragma unroll
    for (int mf = 0; mf < 2; ++mf)
#pragma unroll
      for (int nf = 0; nf < 4; ++nf)
        acc[mf][nf] = __builtin_amdgcn_mfma_f32_16x16x32_bf16(a[mf], b[nf], acc[mf][nf], 0, 0, 0);
    __builtin_amdgcn_s_setprio(0);
    asm volatile("" ::: "memory");
  };

#pragma unroll 4
  for (int ph = 0; ph < NPH - 3; ++ph) {
    __builtin_amdgcn_sched_barrier(0);
    asm volatile("s_waitcnt vmcnt(4)" ::: "memory");
    __builtin_amdgcn_s_barrier();
    stage(ph + 3);
    compute(ph);
  }
  __builtin_amdgcn_sched_barrier(0);
  asm volatile("s_waitcnt vmcnt(4)" ::: "memory");
  __builtin_amdgcn_s_barrier();
  compute(NPH - 3);
  __builtin_amdgcn_sched_barrier(0);
  asm volatile("s_waitcnt vmcnt(2)" ::: "memory");
  __builtin_amdgcn_s_barrier();
  compute(NPH - 2);
  __builtin_amdgcn_sched_barrier(0);
  asm volatile("s_waitcnt vmcnt(0)" ::: "memory");
  __builtin_amdgcn_s_barrier();
  compute(NPH - 1);

#pragma unroll
  for (int mf = 0; mf < 2; ++mf)
#pragma unroll
    for (int nf = 0; nf < 4; ++nf)
#pragma unroll
      for (int rr = 0; rr < 4; ++rr) {
        const size_t cidx = (size_t)(m0 + wr * 32 + mf * 16 + lg * 4 + rr) * N +
                            (n0 + wc * 64 + nf * 16 + lr);
        if (BF16OUT)
          ((u16*)Cout)[cidx] = bfc(acc[mf][nf][rr]);
        else
          ((float*)Cout)[cidx] = acc[mf][nf][rr];
      }
}

// ---------------- flash attention (causal, GQA), swapped-QK^T, STATIC-max softmax.
// RMSNorm bounds |S*log2e| <= 11.6 -> P = exp2(S) directly. Q pre-scaled by
// 0.125*log2(e). LDS addresses hoisted to lane-constant bases + imm offsets.
__global__ __launch_bounds__(256) void attn_fwd(const u16* __restrict__ Q,
                                                const u16* __restrict__ Kb,
                                                const u16* __restrict__ VT,
                                                u16* __restrict__ O) {
  const int h = blockIdx.x & 63;
  const int qb = (S_LEN / 64 - 1) - (blockIdx.x >> 6);  // big blocks first
  const int kvh = h >> 4;
  __shared__ __align__(16) char KV[2 * 16384];  // page: K 8KB | V 8KB
  const int tid = threadIdx.x;
  const int w = tid >> 6, l = tid & 63;
  const int lr = l & 15, lg = l >> 4;

  const int srow = w * 16 + (l >> 3);
  const int s0 = (l & 7) ^ (srow & 7);                          // inverse bank swizzle
  const int sv = (s0 & 4) | ((s0 & 1) << 1) | ((s0 & 2) >> 1);  // + pi for V packs
  const char* Kg = (const char*)Kb + kvh * 128 + (size_t)srow * 512 + s0 * 16;
  const char* Vg = (const char*)VT + (size_t)(kvh * 64 + srow) * (S_LEN * 2) + sv * 16;
  const int wofs = w * 2048;

  auto stage = [&](int page) {
    char* pb = KV + page * 16384 + wofs;
    gll16(Kg, pb);
    gll16(Kg + 8 * 512, pb + 1024);
    gll16(Vg, pb + 8192);
    gll16(Vg + 8 * (S_LEN * 2), pb + 8192 + 1024);
    Kg += 64 * 512;
    Vg += 128;
  };

  bf16x8 qf[2];
  {
    const size_t qoff = (size_t)(qb * 64 + w * 16 + lr) * DMODEL + h * HD + lg * 8;
    qf[0] = *(const bf16x8*)&Q[qoff];
    qf[1] = *(const bf16x8*)&Q[qoff + 32];
  }
  f32x4 o[4] = {};
  float lrow = 0.f;
  const int qlane = qb * 64 + w * 16 + lr;          // this lane's softmax q-row
  const int abase = (l & 48) | ((l >> 2) & 12);     // lane holding q = lg*4+r is abase+r

  const int xr = lr & 7;
  const int kb0 = lr * 128 + ((lg ^ xr) << 4);
  const int kb1 = lr * 128 + (((4 + lg) ^ xr) << 4);
  const int vb0 = 8192 + kb0;
  const int vb1 = 8192 + kb1;

  stage(0);

  for (int t = 0; t <= qb; ++t) {
    __builtin_amdgcn_sched_barrier(0);
    asm volatile("s_waitcnt vmcnt(0)" ::: "memory");
    __builtin_amdgcn_s_barrier();
    __builtin_amdgcn_sched_barrier(0);
    if (t < qb) stage((t + 1) & 1);
    const char* page = KV + (t & 1) * 16384;

    // S^T = K @ Q^T : lane holds S[q=lr][kv = t*64 + ni*16 + lg*4 + r]
    f32x4 sf[4] = {};
#pragma unroll
    for (int ni = 0; ni < 4; ++ni) {
      bf16x8 kf0 = *(const bf16x8*)(page + kb0 + ni * 2048);
      bf16x8 kf1 = *(const bf16x8*)(page + kb1 + ni * 2048);
      sf[ni] = __builtin_amdgcn_mfma_f32_16x16x32_bf16(kf0, qf[0], sf[ni], 0, 0, 0);
      sf[ni] = __builtin_amdgcn_mfma_f32_16x16x32_bf16(kf1, qf[1], sf[ni], 0, 0, 0);
    }
    if (t == qb) {
      const int kvb = t * 64 + lg * 4;
#pragma unroll
      for (int ni = 0; ni < 4; ++ni)
#pragma unroll
        for (int r = 0; r < 4; ++r)
          if (kvb + ni * 16 + r > qlane) sf[ni][r] = -1e30f;
    }
    // static-max softmax: P = exp2(S), bounded by 2^11.6
    float p[4][4];
    float r4[4];
#pragma unroll
    for (int ni = 0; ni < 4; ++ni) {
#pragma unroll
      for (int r = 0; r < 4; ++r) p[ni][r] = ex2(sf[ni][r]);
      r4[ni] = (p[ni][0] + p[ni][1]) + (p[ni][2] + p[ni][3]);
    }
    float rs = (r4[0] + r4[1]) + (r4[2] + r4[3]);
    rs += __shfl_xor(rs, 16, 64);
    rs += __shfl_xor(rs, 32, 64);
    lrow += rs;

    // O += P @ V : build A-fragments in-register (packs + xor16 exchange)
    const bool odd = (lg & 1);
#pragma unroll
    for (int kk = 0; kk < 2; ++kk) {
      const int nA = 2 * kk, nB = 2 * kk + 1;
      const u32 cA0 = pk2(p[nA][0], p[nA][1]), cA1 = pk2(p[nA][2], p[nA][3]);
      const u32 cB0 = pk2(p[nB][0], p[nB][1]), cB1 = pk2(p[nB][2], p[nB][3]);
      const u32 cS0 = odd ? cB0 : cA0, cS1 = odd ? cB1 : cA1;
      const u32 cP0 = odd ? cA0 : cB0, cP1 = odd ? cA1 : cB1;
      const u32 rP0 = (u32)__shfl_xor((int)cP0, 16, 64);
      const u32 rP1 = (u32)__shfl_xor((int)cP1, 16, 64);
      u32x4 wv;
      wv[0] = odd ? rP0 : cS0;
      wv[1] = odd ? rP1 : cS1;
      wv[2] = odd ? cS0 : rP0;
      wv[3] = odd ? cS1 : rP1;
      const bf16x8 pa = __builtin_bit_cast(bf16x8, wv);
      const int vb = kk ? vb1 : vb0;
#pragma unroll
      for (int ni = 0; ni < 4; ++ni) {
        bf16x8 vf = *(const bf16x8*)(page + vb + ni * 2048);
        o[ni] = __builtin_amdgcn_mfma_f32_16x16x32_bf16(pa, vf, o[ni], 0, 0, 0);
      }
    }
  }
  const float lv0 = __shfl(lrow, abase + 0, 64);
  const float lv1 = __shfl(lrow, abase + 1, 64);
  const float lv2 = __shfl(lrow, abase + 2, 64);
  const float lv3 = __shfl(lrow, abase + 3, 64);
  const f32x4 lv = {lv0, lv1, lv2, lv3};
#pragma unroll
  for (int ni = 0; ni < 4; ++ni)
#pragma unroll
    for (int r = 0; r < 4; ++r) {
      const size_t orow = (size_t)(qb * 64 + w * 16 + lg * 4 + r);
      O[orow * DMODEL + h * HD + ni * 16 + lr] = f2bf(o[ni][r] / lv[r]);
    }
}

// ---------------- launcher ----------------
extern "C" void kernel_launch(void* const* d_in, const int* in_sizes, int n_in,
                              void* d_out, int out_size, void* d_ws, size_t ws_size,
                              hipStream_t stream) {
  const float* x   = (const float*)d_in[0];
  const float* wq  = (const float*)d_in[1];
  const float* wk  = (const float*)d_in[2];
  const float* wv  = (const float*)d_in[3];
  const float* wo  = (const float*)d_in[4];
  const float* qnw = (const float*)d_in[5];
  const float* knw = (const float*)d_in[6];
  const float* fc  = (const float*)d_in[7];
  const float* fs  = (const float*)d_in[8];
  float* out = (float*)d_out;

  char* ws = (char*)d_ws;
  size_t off = 0;
  auto alloc = [&](size_t bytes) {
    char* p = ws + off;
    off += (bytes + 255) & ~(size_t)255;
    return p;
  };
  const int NQKV = DMODEL + 512;  // 4608
  u16*   xb    = (u16*)alloc((size_t)S_LEN * DMODEL * 2);
  u16*   wqkvT = (u16*)alloc((size_t)NQKV * DMODEL * 2);
  u16*   woT   = (u16*)alloc((size_t)DMODEL * DMODEL * 2);
  u16*   Pq    = (u16*)alloc((size_t)S_LEN * NQKV * 2);
  u16*   Qn    = (u16*)alloc((size_t)S_LEN * DMODEL * 2);
  u16*   Kn    = (u16*)alloc((size_t)S_LEN * 256 * 2);
  u16*   VTb   = (u16*)alloc((size_t)256 * S_LEN * 2);
  u16*   Ob    = (u16*)alloc((size_t)S_LEN * DMODEL * 2);

  hipFuncSetAttribute((const void*)gemm_mn<1>, hipFuncAttributeMaxDynamicSharedMemorySize, 65536);
  hipFuncSetAttribute((const void*)gemm_mn<0>, hipFuncAttributeMaxDynamicSharedMemorySize, 65536);

  cvt_f32_bf16_v4<<<(S_LEN * DMODEL / 4) / 256, 256, 0, stream>>>(x, xb);
  tconvs<<<(4096 / 32) * (4096 / 32), 256, 0, stream>>>(wq, 4096, wqkvT, 4096, 4096);
  tconvs<<<(4096 / 32) * (256 / 32), 256, 0, stream>>>(wk, 256,
      wqkvT + (size_t)4096 * 4096, 4096, 256);
  tconvs<<<(4096 / 32) * (256 / 32), 256, 0, stream>>>(wv, 256,
      wqkvT + (size_t)4352 * 4096, 4096, 256);
  tconvs<<<(4096 / 32) * (4096 / 32), 256, 0, stream>>>(wo, 4096, woT, 4096, 4096);

  // fused QKV projection: 128x128 tiles -> 16*36 = 576 blocks, bf16 output
  gemm_mn<1><<<(2048 / 128) * (NQKV / 128), 512, 65536, stream>>>(
      xb, wqkvT, Pq, 2048, NQKV, 4096);

  const float QSCALE = 0.125f * 1.44269504088896340736f;
  norm_rope_q<<<(S_LEN * NH) / 4, 256, 0, stream>>>(Pq, NQKV, NH, qnw, fc, fs,
                                                    Qn, DMODEL, QSCALE);
  norm_rope_q<<<(S_LEN * NKV) / 4, 256, 0, stream>>>(Pq + 4096, NQKV, NKV,
                                                     knw, fc, fs, Kn, 256, 1.0f);
  // V^T: bf16 (2048 x 256, row stride 4608) -> VT (256 x 2048)
  tconvb<<<(2048 / 32) * (256 / 32), 256, 0, stream>>>(Pq + 4352, NQKV, VTb, 2048, 256);

  attn_fwd<<<(S_LEN / 64) * NH, 256, 0, stream>>>(Qn, Kn, VTb, Ob);

  // out projection: 128x128 tiles -> 16*32 = 512 blocks, fp32 direct to out
  gemm_mn<0><<<(2048 / 128) * (4096 / 128), 512, 65536, stream>>>(
      Ob, woT, out, 2048, 4096, 4096);
}

// Round 10
// 333.740 us; speedup vs baseline: 1.0728x; 1.0728x over previous
//
#include <hip/hip_runtime.h>
#include <hip/hip_bf16.h>

typedef unsigned short u16;
typedef unsigned int   u32;
typedef __attribute__((ext_vector_type(8))) __bf16 bf16x8;
typedef __attribute__((ext_vector_type(4))) float  f32x4;
typedef __attribute__((ext_vector_type(8))) u16    u16x8;
typedef __attribute__((ext_vector_type(4))) u16    u16x4;
typedef __attribute__((ext_vector_type(2))) u32    u32x2;
typedef __attribute__((ext_vector_type(4))) u32    u32x4;

#define S_LEN 2048
#define DMODEL 4096
#define NH 64
#define NKV 4
#define HD 64

__device__ __forceinline__ u16 f2bf(float f) {
  u32 u = __builtin_bit_cast(u32, f);
  u32 r = (u + 0x7FFFu + ((u >> 16) & 1u)) >> 16;
  return (u16)r;
}
__device__ __forceinline__ u16 bfc(float f) {
  return __builtin_bit_cast(u16, (__bf16)f);
}
__device__ __forceinline__ u32 pk2(float lo, float hi) {
  return (u32)bfc(lo) | ((u32)bfc(hi) << 16);
}
__device__ __forceinline__ float bf2f(u16 u) {
  return __builtin_bit_cast(float, (u32)u << 16);
}
__device__ __forceinline__ float ex2(float x) { return __builtin_amdgcn_exp2f(x); }

__device__ __forceinline__ void gll16(const void* g, void* l) {
  __builtin_amdgcn_global_load_lds(
      (__attribute__((address_space(1))) void*)g,
      (__attribute__((address_space(3))) void*)l, 16, 0, 0);
}

// ---------------- elementwise converts ----------------
__global__ __launch_bounds__(256) void cvt_f32_bf16_v4(const float* __restrict__ in,
                                                       u16* __restrict__ out) {
  const int i = blockIdx.x * 256 + threadIdx.x;
  float4 f = ((const float4*)in)[i];
  u16x4 u = { f2bf(f.x), f2bf(f.y), f2bf(f.z), f2bf(f.w) };
  *(u16x4*)&out[(size_t)i * 4] = u;
}

// transpose-convert: in fp32 R x C (row stride istride) -> out bf16 C x R.
__global__ __launch_bounds__(256) void tconvs(const float* __restrict__ in, int istride,
                                              u16* __restrict__ out, int R, int C) {
  __shared__ __align__(16) float tile[32][36];
  const int nc = C >> 5;
  const int cb = blockIdx.x % nc, rb = blockIdx.x / nc;
  const int r = threadIdx.x >> 3, c4 = (threadIdx.x & 7) << 2;
  float4 v = *(const float4*)&in[(size_t)(rb * 32 + r) * istride + cb * 32 + c4];
  *(float4*)&tile[r][c4] = v;
  __syncthreads();
  u32x2 pr;
  pr[0] = pk2(tile[c4 + 0][r], tile[c4 + 1][r]);
  pr[1] = pk2(tile[c4 + 2][r], tile[c4 + 3][r]);
  *(u32x2*)&out[(size_t)(cb * 32 + r) * R + rb * 32 + c4] = pr;
}

// bf16 transpose: in R x C (row stride istride) -> out C x R.
__global__ __launch_bounds__(256) void tconvb(const u16* __restrict__ in, int istride,
                                              u16* __restrict__ out, int R, int C) {
  __shared__ __align__(16) u16 tile[32][40];
  const int nc = C >> 5;
  const int cb = blockIdx.x % nc, rb = blockIdx.x / nc;
  const int r = threadIdx.x >> 3, c4 = (threadIdx.x & 7) << 2;
  u16x4 v = *(const u16x4*)&in[(size_t)(rb * 32 + r) * istride + cb * 32 + c4];
  *(u16x4*)&tile[r][c4] = v;
  __syncthreads();
  u16x4 o = { tile[c4 + 0][r], tile[c4 + 1][r], tile[c4 + 2][r], tile[c4 + 3][r] };
  *(u16x4*)&out[(size_t)(cb * 32 + r) * R + rb * 32 + c4] = o;
}

// ---------------- RMSNorm + RoPE, bf16 input (one wave = one (s,head) row) ------
__global__ __launch_bounds__(256) void norm_rope_q(const u16* __restrict__ in,
                                                   int in_stride, int nheads,
                                                   const float* __restrict__ nw,
                                                   const float* __restrict__ cosT,
                                                   const float* __restrict__ sinT,
                                                   u16* __restrict__ outp, int out_stride,
                                                   float oscale) {
  const int wid = blockIdx.x * 4 + (threadIdx.x >> 6);
  const int l = threadIdx.x & 63;
  const int s = wid / nheads, h = wid - s * nheads;
  const size_t idx = (size_t)s * in_stride + h * 64 + l;
  const float v = bf2f(in[idx]);
  float sq = v * v;
#pragma unroll
  for (int off = 32; off; off >>= 1) sq += __shfl_xor(sq, off, 64);
  const float rr = rsqrtf(sq * (1.f / 64.f) + 1e-5f);
  const float vn = v * rr * nw[l];
  const float p = __shfl_xor(vn, 1, 64);
  const int i2 = l >> 1;
  const float c = cosT[(size_t)s * 32 + i2];
  const float sn = sinT[(size_t)s * 32 + i2];
  const float o = ((l & 1) ? fmaf(p, sn, vn * c) : fmaf(-p, sn, vn * c)) * oscale;
  outp[(size_t)s * out_stride + h * 64 + l] = f2bf(o);
}

// ---------------- big GEMM: 256(M) x 128(N) tile, FULL-K, 8 waves (4Mx2N, 64x64/wave)
// LDS 72KB = 3 pages x 24KB -> 2 blocks/CU (144KB <= 160KB). Page = 32-k slice
// { A 16KB (256 m) | B 8KB (128 n) }. Depth-2 prefetch, 3 loads/stage, steady
// vmcnt(3). 128B LDS rows pack two rows' 64B k-slices; 16B slots XOR-swizzled.
template <int BF16OUT>
__global__ __launch_bounds__(512, 2) void gemm_mn(const u16* __restrict__ A,
                                                  const u16* __restrict__ Bt,
                                                  void* __restrict__ Cout,
                                                  int M, int N, int K) {
  extern __shared__ __align__(16) char lds[];
  int bid = blockIdx.x;
  const int cpx = gridDim.x >> 3;
  bid = (bid & 7) * cpx + (bid >> 3);
  const int nbn = N >> 7;
  const int bm = bid / nbn, bn = bid % nbn;
  const int m0 = bm << 8, n0 = bn << 7;
  const int t = threadIdx.x, w = t >> 6, l = t & 63;
  const int wr = w >> 1, wc = w & 1;            // waves 4(M) x 2(N); per-wave 64x64
  const int lr = l & 15, lg = l >> 4;

  const int sR = t >> 3, slot = t & 7;
  const int su = slot ^ (sR & 7);
  const int d1 = sR * 128 + slot * 16;
  const u16* Ag = A + (size_t)(m0 + 2 * sR + (su >> 2)) * K + (su & 3) * 8;
  const u16* Bg = Bt + (size_t)(n0 + 2 * sR + (su >> 2)) * K + (su & 3) * 8;
  const size_t r128 = (size_t)128 * K;

  f32x4 acc[4][4] = {};
  const int NPH = K >> 5;

  auto stage = [&](int ph, int pg) {
    const int kofs = ph * 32;
    char* pb = lds + pg * 24576;
    gll16(Ag + kofs, pb + d1);                 // A m 0..127
    gll16(Ag + r128 + kofs, pb + 8192 + d1);   // A m 128..255
    gll16(Bg + kofs, pb + 16384 + d1);         // B n 0..127
  };
  stage(0, 0);
  stage(1, 1);

  const int sfrag = ((lr & 1) << 2) | lg;
  const int swz = (sfrag ^ ((lr >> 1) & 7)) << 4;
  const int aoff = (wr * 32 + (lr >> 1)) * 128 + swz;          // wave covers 64 m = 32 rows
  const int boff = 16384 + (wc * 32 + (lr >> 1)) * 128 + swz;  // wave covers 64 n = 32 rows

  auto compute = [&](int pg) {
    const char* base = lds + pg * 24576;
    bf16x8 a[4], b[4];
#pragma unroll
    for (int mf = 0; mf < 4; ++mf) a[mf] = *(const bf16x8*)(base + aoff + mf * 1024);
#pragma unroll
    for (int nf = 0; nf < 4; ++nf) b[nf] = *(const bf16x8*)(base + boff + nf * 1024);
    __builtin_amdgcn_s_setprio(1);
#pragma unroll
    for (int mf = 0; mf < 4; ++mf)
#pragma unroll
      for (int nf = 0; nf < 4; ++nf)
        acc[mf][nf] = __builtin_amdgcn_mfma_f32_16x16x32_bf16(a[mf], b[nf], acc[mf][nf], 0, 0, 0);
    __builtin_amdgcn_s_setprio(0);
    asm volatile("" ::: "memory");
  };

  int cpg = 0, spg = 2;
  for (int ph = 0; ph < NPH - 2; ++ph) {
    __builtin_amdgcn_sched_barrier(0);
    asm volatile("s_waitcnt vmcnt(3)" ::: "memory");
    __builtin_amdgcn_s_barrier();
    stage(ph + 2, spg);
    compute(cpg);
    cpg = (cpg == 2) ? 0 : cpg + 1;
    spg = (spg == 2) ? 0 : spg + 1;
  }
  __builtin_amdgcn_sched_barrier(0);
  asm volatile("s_waitcnt vmcnt(3)" ::: "memory");
  __builtin_amdgcn_s_barrier();
  compute(cpg);
  cpg = (cpg == 2) ? 0 : cpg + 1;
  __builtin_amdgcn_sched_barrier(0);
  asm volatile("s_waitcnt vmcnt(0)" ::: "memory");
  __builtin_amdgcn_s_barrier();
  compute(cpg);

#pragma unroll
  for (int mf = 0; mf < 4; ++mf)
#pragma unroll
    for (int nf = 0; nf < 4; ++nf)
#pragma unroll
      for (int rr = 0; rr < 4; ++rr) {
        const size_t cidx = (size_t)(m0 + wr * 64 + mf * 16 + lg * 4 + rr) * N +
                            (n0 + wc * 64 + nf * 16 + lr);
        if (BF16OUT)
          ((u16*)Cout)[cidx] = bfc(acc[mf][nf][rr]);
        else
          ((float*)Cout)[cidx] = acc[mf][nf][rr];
      }
}

// ---------------- flash attention (causal, GQA), swapped-QK^T, STATIC-max softmax.
// RMSNorm bounds |S*log2e| <= 11.6 -> P = exp2(S) directly. Q pre-scaled by
// 0.125*log2(e). LDS addresses hoisted to lane-constant bases + imm offsets.
__global__ __launch_bounds__(256) void attn_fwd(const u16* __restrict__ Q,
                                                const u16* __restrict__ Kb,
                                                const u16* __restrict__ VT,
                                                u16* __restrict__ O) {
  const int h = blockIdx.x & 63;
  const int qb = (S_LEN / 64 - 1) - (blockIdx.x >> 6);  // big blocks first
  const int kvh = h >> 4;
  __shared__ __align__(16) char KV[2 * 16384];  // page: K 8KB | V 8KB
  const int tid = threadIdx.x;
  const int w = tid >> 6, l = tid & 63;
  const int lr = l & 15, lg = l >> 4;

  const int srow = w * 16 + (l >> 3);
  const int s0 = (l & 7) ^ (srow & 7);                          // inverse bank swizzle
  const int sv = (s0 & 4) | ((s0 & 1) << 1) | ((s0 & 2) >> 1);  // + pi for V packs
  const char* Kg = (const char*)Kb + kvh * 128 + (size_t)srow * 512 + s0 * 16;
  const char* Vg = (const char*)VT + (size_t)(kvh * 64 + srow) * (S_LEN * 2) + sv * 16;
  const int wofs = w * 2048;

  auto stage = [&](int page) {
    char* pb = KV + page * 16384 + wofs;
    gll16(Kg, pb);
    gll16(Kg + 8 * 512, pb + 1024);
    gll16(Vg, pb + 8192);
    gll16(Vg + 8 * (S_LEN * 2), pb + 8192 + 1024);
    Kg += 64 * 512;
    Vg += 128;
  };

  bf16x8 qf[2];
  {
    const size_t qoff = (size_t)(qb * 64 + w * 16 + lr) * DMODEL + h * HD + lg * 8;
    qf[0] = *(const bf16x8*)&Q[qoff];
    qf[1] = *(const bf16x8*)&Q[qoff + 32];
  }
  f32x4 o[4] = {};
  float lrow = 0.f;
  const int qlane = qb * 64 + w * 16 + lr;          // this lane's softmax q-row
  const int abase = (l & 48) | ((l >> 2) & 12);     // lane holding q = lg*4+r is abase+r

  const int xr = lr & 7;
  const int kb0 = lr * 128 + ((lg ^ xr) << 4);
  const int kb1 = lr * 128 + (((4 + lg) ^ xr) << 4);
  const int vb0 = 8192 + kb0;
  const int vb1 = 8192 + kb1;

  stage(0);

  for (int t = 0; t <= qb; ++t) {
    __builtin_amdgcn_sched_barrier(0);
    asm volatile("s_waitcnt vmcnt(0)" ::: "memory");
    __builtin_amdgcn_s_barrier();
    __builtin_amdgcn_sched_barrier(0);
    if (t < qb) stage((t + 1) & 1);
    const char* page = KV + (t & 1) * 16384;

    // S^T = K @ Q^T : lane holds S[q=lr][kv = t*64 + ni*16 + lg*4 + r]
    f32x4 sf[4] = {};
#pragma unroll
    for (int ni = 0; ni < 4; ++ni) {
      bf16x8 kf0 = *(const bf16x8*)(page + kb0 + ni * 2048);
      bf16x8 kf1 = *(const bf16x8*)(page + kb1 + ni * 2048);
      sf[ni] = __builtin_amdgcn_mfma_f32_16x16x32_bf16(kf0, qf[0], sf[ni], 0, 0, 0);
      sf[ni] = __builtin_amdgcn_mfma_f32_16x16x32_bf16(kf1, qf[1], sf[ni], 0, 0, 0);
    }
    if (t == qb) {
      const int kvb = t * 64 + lg * 4;
#pragma unroll
      for (int ni = 0; ni < 4; ++ni)
#pragma unroll
        for (int r = 0; r < 4; ++r)
          if (kvb + ni * 16 + r > qlane) sf[ni][r] = -1e30f;
    }
    // static-max softmax: P = exp2(S), bounded by 2^11.6
    float p[4][4];
    float r4[4];
#pragma unroll
    for (int ni = 0; ni < 4; ++ni) {
#pragma unroll
      for (int r = 0; r < 4; ++r) p[ni][r] = ex2(sf[ni][r]);
      r4[ni] = (p[ni][0] + p[ni][1]) + (p[ni][2] + p[ni][3]);
    }
    float rs = (r4[0] + r4[1]) + (r4[2] + r4[3]);
    rs += __shfl_xor(rs, 16, 64);
    rs += __shfl_xor(rs, 32, 64);
    lrow += rs;

    // O += P @ V : build A-fragments in-register (packs + xor16 exchange)
    const bool odd = (lg & 1);
#pragma unroll
    for (int kk = 0; kk < 2; ++kk) {
      const int nA = 2 * kk, nB = 2 * kk + 1;
      const u32 cA0 = pk2(p[nA][0], p[nA][1]), cA1 = pk2(p[nA][2], p[nA][3]);
      const u32 cB0 = pk2(p[nB][0], p[nB][1]), cB1 = pk2(p[nB][2], p[nB][3]);
      const u32 cS0 = odd ? cB0 : cA0, cS1 = odd ? cB1 : cA1;
      const u32 cP0 = odd ? cA0 : cB0, cP1 = odd ? cA1 : cB1;
      const u32 rP0 = (u32)__shfl_xor((int)cP0, 16, 64);
      const u32 rP1 = (u32)__shfl_xor((int)cP1, 16, 64);
      u32x4 wv;
      wv[0] = odd ? rP0 : cS0;
      wv[1] = odd ? rP1 : cS1;
      wv[2] = odd ? cS0 : rP0;
      wv[3] = odd ? cS1 : rP1;
      const bf16x8 pa = __builtin_bit_cast(bf16x8, wv);
      const int vb = kk ? vb1 : vb0;
#pragma unroll
      for (int ni = 0; ni < 4; ++ni) {
        bf16x8 vf = *(const bf16x8*)(page + vb + ni * 2048);
        o[ni] = __builtin_amdgcn_mfma_f32_16x16x32_bf16(pa, vf, o[ni], 0, 0, 0);
      }
    }
  }
  const float lv0 = __shfl(lrow, abase + 0, 64);
  const float lv1 = __shfl(lrow, abase + 1, 64);
  const float lv2 = __shfl(lrow, abase + 2, 64);
  const float lv3 = __shfl(lrow, abase + 3, 64);
  const f32x4 lv = {lv0, lv1, lv2, lv3};
#pragma unroll
  for (int ni = 0; ni < 4; ++ni)
#pragma unroll
    for (int r = 0; r < 4; ++r) {
      const size_t orow = (size_t)(qb * 64 + w * 16 + lg * 4 + r);
      O[orow * DMODEL + h * HD + ni * 16 + lr] = f2bf(o[ni][r] / lv[r]);
    }
}

// ---------------- launcher ----------------
extern "C" void kernel_launch(void* const* d_in, const int* in_sizes, int n_in,
                              void* d_out, int out_size, void* d_ws, size_t ws_size,
                              hipStream_t stream) {
  const float* x   = (const float*)d_in[0];
  const float* wq  = (const float*)d_in[1];
  const float* wk  = (const float*)d_in[2];
  const float* wv  = (const float*)d_in[3];
  const float* wo  = (const float*)d_in[4];
  const float* qnw = (const float*)d_in[5];
  const float* knw = (const float*)d_in[6];
  const float* fc  = (const float*)d_in[7];
  const float* fs  = (const float*)d_in[8];
  float* out = (float*)d_out;

  char* ws = (char*)d_ws;
  size_t off = 0;
  auto alloc = [&](size_t bytes) {
    char* p = ws + off;
    off += (bytes + 255) & ~(size_t)255;
    return p;
  };
  const int NQKV = DMODEL + 512;  // 4608
  u16*   xb    = (u16*)alloc((size_t)S_LEN * DMODEL * 2);
  u16*   wqkvT = (u16*)alloc((size_t)NQKV * DMODEL * 2);
  u16*   woT   = (u16*)alloc((size_t)DMODEL * DMODEL * 2);
  u16*   Pq    = (u16*)alloc((size_t)S_LEN * NQKV * 2);
  u16*   Qn    = (u16*)alloc((size_t)S_LEN * DMODEL * 2);
  u16*   Kn    = (u16*)alloc((size_t)S_LEN * 256 * 2);
  u16*   VTb   = (u16*)alloc((size_t)256 * S_LEN * 2);
  u16*   Ob    = (u16*)alloc((size_t)S_LEN * DMODEL * 2);

  hipFuncSetAttribute((const void*)gemm_mn<1>, hipFuncAttributeMaxDynamicSharedMemorySize, 73728);
  hipFuncSetAttribute((const void*)gemm_mn<0>, hipFuncAttributeMaxDynamicSharedMemorySize, 73728);

  cvt_f32_bf16_v4<<<(S_LEN * DMODEL / 4) / 256, 256, 0, stream>>>(x, xb);
  tconvs<<<(4096 / 32) * (4096 / 32), 256, 0, stream>>>(wq, 4096, wqkvT, 4096, 4096);
  tconvs<<<(4096 / 32) * (256 / 32), 256, 0, stream>>>(wk, 256,
      wqkvT + (size_t)4096 * 4096, 4096, 256);
  tconvs<<<(4096 / 32) * (256 / 32), 256, 0, stream>>>(wv, 256,
      wqkvT + (size_t)4352 * 4096, 4096, 256);
  tconvs<<<(4096 / 32) * (4096 / 32), 256, 0, stream>>>(wo, 4096, woT, 4096, 4096);

  // fused QKV projection: 256x128 tiles -> 8*36 = 288 blocks (<= 512 resident)
  gemm_mn<1><<<(2048 / 256) * (NQKV / 128), 512, 73728, stream>>>(
      xb, wqkvT, Pq, 2048, NQKV, 4096);

  const float QSCALE = 0.125f * 1.44269504088896340736f;
  norm_rope_q<<<(S_LEN * NH) / 4, 256, 0, stream>>>(Pq, NQKV, NH, qnw, fc, fs,
                                                    Qn, DMODEL, QSCALE);
  norm_rope_q<<<(S_LEN * NKV) / 4, 256, 0, stream>>>(Pq + 4096, NQKV, NKV,
                                                     knw, fc, fs, Kn, 256, 1.0f);
  // V^T: bf16 (2048 x 256, row stride 4608) -> VT (256 x 2048)
  tconvb<<<(2048 / 32) * (256 / 32), 256, 0, stream>>>(Pq + 4352, NQKV, VTb, 2048, 256);

  attn_fwd<<<(S_LEN / 64) * NH, 256, 0, stream>>>(Qn, Kn, VTb, Ob);

  // out projection: 256x128 tiles -> 8*32 = 256 blocks, fp32 direct to out
  gemm_mn<0><<<(2048 / 256) * (4096 / 128), 512, 73728, stream>>>(
      Ob, woT, out, 2048, 4096, 4096);
}

// Round 11
// 332.934 us; speedup vs baseline: 1.0754x; 1.0024x over previous
//
#include <hip/hip_runtime.h>
#include <hip/hip_bf16.h>

typedef unsigned short u16;
typedef unsigned int   u32;
typedef __attribute__((ext_vector_type(8))) __bf16 bf16x8;
typedef __attribute__((ext_vector_type(4))) float  f32x4;
typedef __attribute__((ext_vector_type(8))) u16    u16x8;
typedef __attribute__((ext_vector_type(4))) u16    u16x4;
typedef __attribute__((ext_vector_type(2))) u32    u32x2;
typedef __attribute__((ext_vector_type(4))) u32    u32x4;

#define S_LEN 2048
#define DMODEL 4096
#define NH 64
#define NKV 4
#define HD 64

__device__ __forceinline__ u16 f2bf(float f) {
  u32 u = __builtin_bit_cast(u32, f);
  u32 r = (u + 0x7FFFu + ((u >> 16) & 1u)) >> 16;
  return (u16)r;
}
__device__ __forceinline__ u16 bfc(float f) {
  return __builtin_bit_cast(u16, (__bf16)f);
}
__device__ __forceinline__ u32 pk2(float lo, float hi) {
  return (u32)bfc(lo) | ((u32)bfc(hi) << 16);
}
__device__ __forceinline__ float bf2f(u16 u) {
  return __builtin_bit_cast(float, (u32)u << 16);
}
__device__ __forceinline__ float ex2(float x) { return __builtin_amdgcn_exp2f(x); }

__device__ __forceinline__ void gll16(const void* g, void* l) {
  __builtin_amdgcn_global_load_lds(
      (__attribute__((address_space(1))) void*)g,
      (__attribute__((address_space(3))) void*)l, 16, 0, 0);
}

// ---------------- elementwise converts ----------------
__global__ __launch_bounds__(256) void cvt_f32_bf16_v4(const float* __restrict__ in,
                                                       u16* __restrict__ out) {
  const int i = blockIdx.x * 256 + threadIdx.x;
  float4 f = ((const float4*)in)[i];
  u16x4 u = { f2bf(f.x), f2bf(f.y), f2bf(f.z), f2bf(f.w) };
  *(u16x4*)&out[(size_t)i * 4] = u;
}

// transpose-convert (optionally summing two fp32 srcs): in R x C (row stride istride)
// -> out bf16 C x R
__global__ __launch_bounds__(256) void tconvs(const float* __restrict__ in,
                                              const float* __restrict__ in2, int istride,
                                              u16* __restrict__ out, int R, int C) {
  __shared__ __align__(16) float tile[32][36];
  const int nc = C >> 5;
  const int cb = blockIdx.x % nc, rb = blockIdx.x / nc;
  const int r = threadIdx.x >> 3, c4 = (threadIdx.x & 7) << 2;
  const size_t idx = (size_t)(rb * 32 + r) * istride + cb * 32 + c4;
  float4 v = *(const float4*)&in[idx];
  if (in2) {
    float4 u = *(const float4*)&in2[idx];
    v.x += u.x; v.y += u.y; v.z += u.z; v.w += u.w;
  }
  *(float4*)&tile[r][c4] = v;
  __syncthreads();
  u32x2 pr;
  pr[0] = pk2(tile[c4 + 0][r], tile[c4 + 1][r]);
  pr[1] = pk2(tile[c4 + 2][r], tile[c4 + 3][r]);
  *(u32x2*)&out[(size_t)(cb * 32 + r) * R + rb * 32 + c4] = pr;
}

// ---------------- RMSNorm + RoPE, fp32 dual-partial input (K path) ------------
__global__ __launch_bounds__(256) void norm_rope(const float* __restrict__ in,
                                                 const float* __restrict__ in2,
                                                 int in_stride, int nheads,
                                                 const float* __restrict__ nw,
                                                 const float* __restrict__ cosT,
                                                 const float* __restrict__ sinT,
                                                 u16* __restrict__ outp, int out_stride,
                                                 float oscale) {
  const int wid = blockIdx.x * 4 + (threadIdx.x >> 6);
  const int l = threadIdx.x & 63;
  const int s = wid / nheads, h = wid - s * nheads;
  const size_t idx = (size_t)s * in_stride + h * 64 + l;
  const float v = in[idx] + in2[idx];
  float sq = v * v;
#pragma unroll
  for (int off = 32; off; off >>= 1) sq += __shfl_xor(sq, off, 64);
  const float rr = rsqrtf(sq * (1.f / 64.f) + 1e-5f);
  const float vn = v * rr * nw[l];
  const float p = __shfl_xor(vn, 1, 64);
  const int i2 = l >> 1;
  const float c = cosT[(size_t)s * 32 + i2];
  const float sn = sinT[(size_t)s * 32 + i2];
  const float o = ((l & 1) ? fmaf(p, sn, vn * c) : fmaf(-p, sn, vn * c)) * oscale;
  outp[(size_t)s * out_stride + h * 64 + l] = f2bf(o);
}

// ---------------- RMSNorm + RoPE, bf16 single input (Q path) ------------
__global__ __launch_bounds__(256) void norm_rope_q(const u16* __restrict__ in,
                                                   int in_stride, int nheads,
                                                   const float* __restrict__ nw,
                                                   const float* __restrict__ cosT,
                                                   const float* __restrict__ sinT,
                                                   u16* __restrict__ outp, int out_stride,
                                                   float oscale) {
  const int wid = blockIdx.x * 4 + (threadIdx.x >> 6);
  const int l = threadIdx.x & 63;
  const int s = wid / nheads, h = wid - s * nheads;
  const size_t idx = (size_t)s * in_stride + h * 64 + l;
  const float v = bf2f(in[idx]);
  float sq = v * v;
#pragma unroll
  for (int off = 32; off; off >>= 1) sq += __shfl_xor(sq, off, 64);
  const float rr = rsqrtf(sq * (1.f / 64.f) + 1e-5f);
  const float vn = v * rr * nw[l];
  const float p = __shfl_xor(vn, 1, 64);
  const int i2 = l >> 1;
  const float c = cosT[(size_t)s * 32 + i2];
  const float sn = sinT[(size_t)s * 32 + i2];
  const float o = ((l & 1) ? fmaf(p, sn, vn * c) : fmaf(-p, sn, vn * c)) * oscale;
  outp[(size_t)s * out_stride + h * 64 + l] = f2bf(o);
}

// ---------------- KV projection: 128x128 tiles, split-K=2 ----------------
__global__ __launch_bounds__(256) void gemm_kv(const u16* __restrict__ A,
                                               const u16* __restrict__ Bt,
                                               float* __restrict__ C0,
                                               float* __restrict__ C1,
                                               int M, int N, int K) {
  __shared__ __align__(16) u16 As[128 * 32];
  __shared__ __align__(16) u16 Bs[128 * 32];
  int bid = blockIdx.x;
  const int cpx = gridDim.x >> 3;
  bid = (bid & 7) * cpx + (bid >> 3);
  const int nbn = N >> 7;
  const int pertile = (M >> 7) * nbn;
  const int sl = bid / pertile;
  const int rem = bid - sl * pertile;
  const int bm = rem / nbn, bn = rem % nbn;
  const int m0 = bm << 7, n0 = bn << 7;
  const int tid = threadIdx.x;
  const int w = tid >> 6, l = tid & 63;
  const int wr = w >> 1, wc = w & 1;
  f32x4 acc[4][4] = {};

  const int Khalf = K >> 1;
  const int kbase = sl * Khalf;

  const char* Ag = (const char*)A +
      ((size_t)(m0 + w * 32 + (l >> 2)) * K + kbase + (l & 3) * 8) * 2;
  const char* Bg = (const char*)Bt +
      ((size_t)(n0 + w * 32 + (l >> 2)) * K + kbase + (l & 3) * 8) * 2;
  char* Al = (char*)As + (w * 32) * 64;
  char* Bl = (char*)Bs + (w * 32) * 64;
  const size_t rowadv = (size_t)16 * K * 2;

  for (int k0 = 0; k0 < Khalf; k0 += 32) {
    gll16(Ag, Al);
    gll16(Ag + rowadv, Al + 1024);
    gll16(Bg, Bl);
    gll16(Bg + rowadv, Bl + 1024);
    Ag += 64; Bg += 64;
    __syncthreads();
    bf16x8 af[4], bq[4];
#pragma unroll
    for (int i = 0; i < 4; ++i) {
      af[i] = *(const bf16x8*)&As[(wr * 64 + i * 16 + (l & 15)) * 32 + (l >> 4) * 8];
      bq[i] = *(const bf16x8*)&Bs[(wc * 64 + i * 16 + (l & 15)) * 32 + (l >> 4) * 8];
    }
#pragma unroll
    for (int mi = 0; mi < 4; ++mi)
#pragma unroll
      for (int ni = 0; ni < 4; ++ni)
        acc[mi][ni] = __builtin_amdgcn_mfma_f32_16x16x32_bf16(af[mi], bq[ni], acc[mi][ni], 0, 0, 0);
    __syncthreads();
  }
  float* Cs = sl ? C1 : C0;
  const int r0 = (l >> 4) * 4, c0 = l & 15;
#pragma unroll
  for (int mi = 0; mi < 4; ++mi)
#pragma unroll
    for (int ni = 0; ni < 4; ++ni)
#pragma unroll
      for (int r = 0; r < 4; ++r)
        Cs[(size_t)(m0 + wr * 64 + mi * 16 + r0 + r) * N + (n0 + wc * 64 + ni * 16 + c0)] =
            acc[mi][ni][r];
}

// ---------------- big GEMM: 256(M) x 128(N) tile, FULL-K (=4096), 8 waves ----
// BK=64 phases: one vmcnt+barrier per 64-k (half the sync count of the 32-k
// version). LDS 144KB = 3 pages x 48KB; page = 64-k { two 24KB 32-k sub-slices
// of {A 16KB | B 8KB} }. Depth-2 prefetch (12 loads in flight, steady vmcnt(6)),
// ALL page indices compile-time static (unroll-by-3 main loop + explicit tail).
// 128B LDS rows pack two rows' 64B k-slices; 16B slots XOR-swizzled.
template <int BF16OUT>
__global__ __launch_bounds__(512, 2) void gemm_mn(const u16* __restrict__ A,
                                                  const u16* __restrict__ Bt,
                                                  void* __restrict__ Cout,
                                                  int M, int N, int K) {
  extern __shared__ __align__(16) char lds[];
  int bid = blockIdx.x;
  const int cpx = gridDim.x >> 3;
  bid = (bid & 7) * cpx + (bid >> 3);
  const int nbn = N >> 7;
  const int bm = bid / nbn, bn = bid % nbn;
  const int m0 = bm << 8, n0 = bn << 7;
  const int t = threadIdx.x, w = t >> 6, l = t & 63;
  const int wr = w >> 1, wc = w & 1;            // waves 4(M) x 2(N); per-wave 64x64
  const int lr = l & 15, lg = l >> 4;

  const int sR = t >> 3, slot = t & 7;
  const int su = slot ^ (sR & 7);
  const int d1 = sR * 128 + slot * 16;
  const u16* Ag = A + (size_t)(m0 + 2 * sR + (su >> 2)) * K + (su & 3) * 8;
  const u16* Bg = Bt + (size_t)(n0 + 2 * sR + (su >> 2)) * K + (su & 3) * 8;
  const size_t r128 = (size_t)128 * K;

  f32x4 acc[4][4] = {};

  // stage one 64-k page (6 x gll16): sub0 = k..k+31, sub1 = k+32..k+63
  auto stage = [&](int ph, const int pg) {
    const int k0 = ph * 64;
    char* pb = lds + pg * 49152;
    gll16(Ag + k0, pb + d1);
    gll16(Ag + r128 + k0, pb + 8192 + d1);
    gll16(Bg + k0, pb + 16384 + d1);
    gll16(Ag + k0 + 32, pb + 24576 + d1);
    gll16(Ag + r128 + k0 + 32, pb + 32768 + d1);
    gll16(Bg + k0 + 32, pb + 40960 + d1);
  };
  stage(0, 0);
  stage(1, 1);

  const int sfrag = ((lr & 1) << 2) | lg;
  const int swz = (sfrag ^ ((lr >> 1) & 7)) << 4;
  const int aoff = (wr * 32 + (lr >> 1)) * 128 + swz;
  const int boff = 16384 + (wc * 32 + (lr >> 1)) * 128 + swz;

  auto half = [&](const char* base) {
    bf16x8 a[4], b[4];
#pragma unroll
    for (int mf = 0; mf < 4; ++mf) a[mf] = *(const bf16x8*)(base + aoff + mf * 1024);
#pragma unroll
    for (int nf = 0; nf < 4; ++nf) b[nf] = *(const bf16x8*)(base + boff + nf * 1024);
    __builtin_amdgcn_s_setprio(1);
#pragma unroll
    for (int mf = 0; mf < 4; ++mf)
#pragma unroll
      for (int nf = 0; nf < 4; ++nf)
        acc[mf][nf] = __builtin_amdgcn_mfma_f32_16x16x32_bf16(a[mf], b[nf], acc[mf][nf], 0, 0, 0);
    __builtin_amdgcn_s_setprio(0);
    asm volatile("" ::: "memory");
  };
  auto compute = [&](const int pg) {
    const char* base = lds + pg * 49152;
    half(base);
    half(base + 24576);
  };

#define SYNC6 __builtin_amdgcn_sched_barrier(0); \
  asm volatile("s_waitcnt vmcnt(6)" ::: "memory"); \
  __builtin_amdgcn_s_barrier();
#define SYNC0 __builtin_amdgcn_sched_barrier(0); \
  asm volatile("s_waitcnt vmcnt(0)" ::: "memory"); \
  __builtin_amdgcn_s_barrier();

  // NPH = K/64 = 64 (K is 4096 for all users of this kernel).
  for (int b = 0; b < 60; b += 3) {
    SYNC6; stage(b + 2, 2); compute(0);
    SYNC6; stage(b + 3, 0); compute(1);
    SYNC6; stage(b + 4, 1); compute(2);
  }
  SYNC6; stage(62, 2); compute(0);   // ph 60
  SYNC6; stage(63, 0); compute(1);   // ph 61
  SYNC6; compute(2);                 // ph 62
  SYNC0; compute(0);                 // ph 63
#undef SYNC6
#undef SYNC0

#pragma unroll
  for (int mf = 0; mf < 4; ++mf)
#pragma unroll
    for (int nf = 0; nf < 4; ++nf)
#pragma unroll
      for (int rr = 0; rr < 4; ++rr) {
        const size_t cidx = (size_t)(m0 + wr * 64 + mf * 16 + lg * 4 + rr) * N +
                            (n0 + wc * 64 + nf * 16 + lr);
        if (BF16OUT)
          ((u16*)Cout)[cidx] = bfc(acc[mf][nf][rr]);
        else
          ((float*)Cout)[cidx] = acc[mf][nf][rr];
      }
}

// ---------------- flash attention (causal, GQA), swapped-QK^T, STATIC-max softmax.
// RMSNorm bounds |S*log2e| <= 11.6 -> P = exp2(S) directly. Q pre-scaled by
// 0.125*log2(e). LDS addresses hoisted to lane-constant bases + imm offsets.
__global__ __launch_bounds__(256) void attn_fwd(const u16* __restrict__ Q,
                                                const u16* __restrict__ Kb,
                                                const u16* __restrict__ VT,
                                                u16* __restrict__ O) {
  const int h = blockIdx.x & 63;
  const int qb = (S_LEN / 64 - 1) - (blockIdx.x >> 6);  // big blocks first
  const int kvh = h >> 4;
  __shared__ __align__(16) char KV[2 * 16384];  // page: K 8KB | V 8KB
  const int tid = threadIdx.x;
  const int w = tid >> 6, l = tid & 63;
  const int lr = l & 15, lg = l >> 4;

  const int srow = w * 16 + (l >> 3);
  const int s0 = (l & 7) ^ (srow & 7);                          // inverse bank swizzle
  const int sv = (s0 & 4) | ((s0 & 1) << 1) | ((s0 & 2) >> 1);  // + pi for V packs
  const char* Kg = (const char*)Kb + kvh * 128 + (size_t)srow * 512 + s0 * 16;
  const char* Vg = (const char*)VT + (size_t)(kvh * 64 + srow) * (S_LEN * 2) + sv * 16;
  const int wofs = w * 2048;

  auto stage = [&](int page) {
    char* pb = KV + page * 16384 + wofs;
    gll16(Kg, pb);
    gll16(Kg + 8 * 512, pb + 1024);
    gll16(Vg, pb + 8192);
    gll16(Vg + 8 * (S_LEN * 2), pb + 8192 + 1024);
    Kg += 64 * 512;
    Vg += 128;
  };

  bf16x8 qf[2];
  {
    const size_t qoff = (size_t)(qb * 64 + w * 16 + lr) * DMODEL + h * HD + lg * 8;
    qf[0] = *(const bf16x8*)&Q[qoff];
    qf[1] = *(const bf16x8*)&Q[qoff + 32];
  }
  f32x4 o[4] = {};
  float lrow = 0.f;
  const int qlane = qb * 64 + w * 16 + lr;          // this lane's softmax q-row
  const int abase = (l & 48) | ((l >> 2) & 12);     // lane holding q = lg*4+r is abase+r

  const int xr = lr & 7;
  const int kb0 = lr * 128 + ((lg ^ xr) << 4);
  const int kb1 = lr * 128 + (((4 + lg) ^ xr) << 4);
  const int vb0 = 8192 + kb0;
  const int vb1 = 8192 + kb1;

  stage(0);

  for (int t = 0; t <= qb; ++t) {
    __builtin_amdgcn_sched_barrier(0);
    asm volatile("s_waitcnt vmcnt(0)" ::: "memory");
    __builtin_amdgcn_s_barrier();
    __builtin_amdgcn_sched_barrier(0);
    if (t < qb) stage((t + 1) & 1);
    const char* page = KV + (t & 1) * 16384;

    // S^T = K @ Q^T : lane holds S[q=lr][kv = t*64 + ni*16 + lg*4 + r]
    f32x4 sf[4] = {};
#pragma unroll
    for (int ni = 0; ni < 4; ++ni) {
      bf16x8 kf0 = *(const bf16x8*)(page + kb0 + ni * 2048);
      bf16x8 kf1 = *(const bf16x8*)(page + kb1 + ni * 2048);
      sf[ni] = __builtin_amdgcn_mfma_f32_16x16x32_bf16(kf0, qf[0], sf[ni], 0, 0, 0);
      sf[ni] = __builtin_amdgcn_mfma_f32_16x16x32_bf16(kf1, qf[1], sf[ni], 0, 0, 0);
    }
    if (t == qb) {
      const int kvb = t * 64 + lg * 4;
#pragma unroll
      for (int ni = 0; ni < 4; ++ni)
#pragma unroll
        for (int r = 0; r < 4; ++r)
          if (kvb + ni * 16 + r > qlane) sf[ni][r] = -1e30f;
    }
    // static-max softmax: P = exp2(S), bounded by 2^11.6
    float p[4][4];
    float r4[4];
#pragma unroll
    for (int ni = 0; ni < 4; ++ni) {
#pragma unroll
      for (int r = 0; r < 4; ++r) p[ni][r] = ex2(sf[ni][r]);
      r4[ni] = (p[ni][0] + p[ni][1]) + (p[ni][2] + p[ni][3]);
    }
    float rs = (r4[0] + r4[1]) + (r4[2] + r4[3]);
    rs += __shfl_xor(rs, 16, 64);
    rs += __shfl_xor(rs, 32, 64);
    lrow += rs;

    // O += P @ V : build A-fragments in-register (packs + xor16 exchange)
    const bool odd = (lg & 1);
#pragma unroll
    for (int kk = 0; kk < 2; ++kk) {
      const int nA = 2 * kk, nB = 2 * kk + 1;
      const u32 cA0 = pk2(p[nA][0], p[nA][1]), cA1 = pk2(p[nA][2], p[nA][3]);
      const u32 cB0 = pk2(p[nB][0], p[nB][1]), cB1 = pk2(p[nB][2], p[nB][3]);
      const u32 cS0 = odd ? cB0 : cA0, cS1 = odd ? cB1 : cA1;
      const u32 cP0 = odd ? cA0 : cB0, cP1 = odd ? cA1 : cB1;
      const u32 rP0 = (u32)__shfl_xor((int)cP0, 16, 64);
      const u32 rP1 = (u32)__shfl_xor((int)cP1, 16, 64);
      u32x4 wv;
      wv[0] = odd ? rP0 : cS0;
      wv[1] = odd ? rP1 : cS1;
      wv[2] = odd ? cS0 : rP0;
      wv[3] = odd ? cS1 : rP1;
      const bf16x8 pa = __builtin_bit_cast(bf16x8, wv);
      const int vb = kk ? vb1 : vb0;
#pragma unroll
      for (int ni = 0; ni < 4; ++ni) {
        bf16x8 vf = *(const bf16x8*)(page + vb + ni * 2048);
        o[ni] = __builtin_amdgcn_mfma_f32_16x16x32_bf16(pa, vf, o[ni], 0, 0, 0);
      }
    }
  }
  const float lv0 = __shfl(lrow, abase + 0, 64);
  const float lv1 = __shfl(lrow, abase + 1, 64);
  const float lv2 = __shfl(lrow, abase + 2, 64);
  const float lv3 = __shfl(lrow, abase + 3, 64);
  const f32x4 lv = {lv0, lv1, lv2, lv3};
#pragma unroll
  for (int ni = 0; ni < 4; ++ni)
#pragma unroll
    for (int r = 0; r < 4; ++r) {
      const size_t orow = (size_t)(qb * 64 + w * 16 + lg * 4 + r);
      O[orow * DMODEL + h * HD + ni * 16 + lr] = f2bf(o[ni][r] / lv[r]);
    }
}

// ---------------- launcher ----------------
extern "C" void kernel_launch(void* const* d_in, const int* in_sizes, int n_in,
                              void* d_out, int out_size, void* d_ws, size_t ws_size,
                              hipStream_t stream) {
  const float* x   = (const float*)d_in[0];
  const float* wq  = (const float*)d_in[1];
  const float* wk  = (const float*)d_in[2];
  const float* wv  = (const float*)d_in[3];
  const float* wo  = (const float*)d_in[4];
  const float* qnw = (const float*)d_in[5];
  const float* knw = (const float*)d_in[6];
  const float* fc  = (const float*)d_in[7];
  const float* fs  = (const float*)d_in[8];
  float* out = (float*)d_out;

  char* ws = (char*)d_ws;
  size_t off = 0;
  auto alloc = [&](size_t bytes) {
    char* p = ws + off;
    off += (bytes + 255) & ~(size_t)255;
    return p;
  };
  u16*   xb    = (u16*)alloc((size_t)S_LEN * DMODEL * 2);
  u16*   wqT   = (u16*)alloc((size_t)DMODEL * DMODEL * 2);
  u16*   wkvT  = (u16*)alloc((size_t)512 * DMODEL * 2);
  u16*   woT   = (u16*)alloc((size_t)DMODEL * DMODEL * 2);
  u16*   Pq    = (u16*)alloc((size_t)S_LEN * DMODEL * 2);
  float* KV0   = (float*)alloc((size_t)S_LEN * 512 * 4);
  float* KV1   = (float*)alloc((size_t)S_LEN * 512 * 4);
  u16*   Qn    = (u16*)alloc((size_t)S_LEN * DMODEL * 2);
  u16*   Kn    = (u16*)alloc((size_t)S_LEN * 256 * 2);
  u16*   VTb   = (u16*)alloc((size_t)256 * S_LEN * 2);
  u16*   Ob    = (u16*)alloc((size_t)S_LEN * DMODEL * 2);

  hipFuncSetAttribute((const void*)gemm_mn<1>, hipFuncAttributeMaxDynamicSharedMemorySize, 147456);
  hipFuncSetAttribute((const void*)gemm_mn<0>, hipFuncAttributeMaxDynamicSharedMemorySize, 147456);

  cvt_f32_bf16_v4<<<(S_LEN * DMODEL / 4) / 256, 256, 0, stream>>>(x, xb);
  tconvs<<<(4096 / 32) * (4096 / 32), 256, 0, stream>>>(wq, nullptr, 4096, wqT, 4096, 4096);
  tconvs<<<(4096 / 32) * (256 / 32), 256, 0, stream>>>(wk, nullptr, 256, wkvT, 4096, 256);
  tconvs<<<(4096 / 32) * (256 / 32), 256, 0, stream>>>(wv, nullptr, 256,
      wkvT + (size_t)256 * 4096, 4096, 256);
  tconvs<<<(4096 / 32) * (4096 / 32), 256, 0, stream>>>(wo, nullptr, 4096, woT, 4096, 4096);

  // Q projection: full-K 256x128 tiles -> 8*32 = 256 blocks, bf16 output
  gemm_mn<1><<<(2048 / 256) * (4096 / 128), 512, 147456, stream>>>(
      xb, wqT, Pq, 2048, 4096, 4096);
  // KV projection: split-K2, 128 blocks, fp32 partials
  gemm_kv<<<2 * (2048 / 128) * (512 / 128), 256, 0, stream>>>(
      xb, wkvT, KV0, KV1, 2048, 512, 4096);

  const float QSCALE = 0.125f * 1.44269504088896340736f;
  norm_rope_q<<<(S_LEN * NH) / 4, 256, 0, stream>>>(Pq, DMODEL, NH, qnw, fc, fs,
                                                    Qn, DMODEL, QSCALE);
  norm_rope<<<(S_LEN * NKV) / 4, 256, 0, stream>>>(KV0, KV1, 512, NKV,
                                                   knw, fc, fs, Kn, 256, 1.0f);
  // V^T: V partials (2048 x 256, row stride 512) -> VT (256 x 2048 bf16)
  tconvs<<<(2048 / 32) * (256 / 32), 256, 0, stream>>>(KV0 + 256, KV1 + 256, 512,
                                                       VTb, 2048, 256);

  attn_fwd<<<(S_LEN / 64) * NH, 256, 0, stream>>>(Qn, Kn, VTb, Ob);

  // out projection: full-K 256x128 tiles -> 256 blocks, fp32 direct to out
  gemm_mn<0><<<(2048 / 256) * (4096 / 128), 512, 147456, stream>>>(
      Ob, woT, out, 2048, 4096, 4096);
}